// Round 6
// baseline (84.157 us; speedup 1.0000x reference)
//
#include <hip/hip_runtime.h>
#include <cstdint>
#include <cstddef>

#define NROWS 100000
#define FIN 512
#define HIDDEN 256
#define NCLS 50

typedef __attribute__((ext_vector_type(8))) short s16x8;
typedef __attribute__((ext_vector_type(4))) float f32x4;

__device__ __forceinline__ unsigned short f2bf(float f) {
  unsigned int u = __float_as_uint(f);
  u += 0x7fffu + ((u >> 16) & 1u);
  return (unsigned short)(u >> 16);
}

// packed fp32x2 -> bf16x2 (RNE), single VALU op
__device__ __forceinline__ unsigned int cvt_pk_bf16(float lo, float hi) {
  unsigned int r;
  asm("v_cvt_pk_bf16_f32 %0, %1, %2" : "=v"(r) : "v"(lo), "v"(hi));
  return r;
}

__device__ __forceinline__ void gload_lds16(const void* g, void* l) {
  __builtin_amdgcn_global_load_lds(
      (const __attribute__((address_space(1))) void*)g,
      (__attribute__((address_space(3))) void*)l, 16, 0, 0);
}

__device__ __forceinline__ f32x4 mfma_bf16(s16x8 a, s16x8 b, f32x4 c) {
  return __builtin_amdgcn_mfma_f32_16x16x32_bf16(a, b, c, 0, 0, 0);
}

// prep: w1t[n][k] = bf16(W1[k][n])  [256][512]   (blocks 0..31, LDS transpose)
//       w2t[c][k] = bf16(W2[k][c]), c>=50 -> 0   [64][256]   (blocks 32..35)
__global__ __launch_bounds__(256) void prep_kernel(
    const float* __restrict__ W1, const float* __restrict__ W2,
    unsigned short* __restrict__ w1t, unsigned short* __restrict__ w2t) {
  __shared__ float tile[64][65];
  const int b = blockIdx.x, t = threadIdx.x;
  if (b < 32) {
    const int k0 = (b >> 2) * 64, n0 = (b & 3) * 64;
    const int rq = t >> 6, col = t & 63;
#pragma unroll
    for (int i = 0; i < 16; ++i) {
      int row = i * 4 + rq;
      tile[row][col] = W1[(size_t)(k0 + row) * HIDDEN + n0 + col];
    }
    __syncthreads();
#pragma unroll
    for (int i = 0; i < 16; ++i) {
      int n = i * 4 + rq;
      w1t[(size_t)(n0 + n) * FIN + k0 + col] = f2bf(tile[col][n]);
    }
  } else {
    const int b2i = b - 32;
#pragma unroll
    for (int i = 0; i < 16; ++i) {
      int idx = t + i * 256;
      int c = idx >> 6;
      int k = b2i * 64 + (idx & 63);
      float v = (c < NCLS) ? W2[(size_t)k * NCLS + c] : 0.0f;
      w2t[(size_t)c * HIDDEN + k] = f2bf(v);
    }
  }
}

// Fused: out = log_softmax(relu(x@W1+b1) @ W2 + b2)
// 256 threads / 4 waves (1M x 4N), tile 64 rows x 256 cols, BK=32.
// A: global fp32 -> regs (2 steps ahead) -> cvt_pk bf16 -> ds_write_b128
//    into linear [64][32] bf16 tile (4KB/buf, conflict-free by construction).
// B: w1t bf16 via global_load_lds, XOR-chunk swizzle, 16KB/buf.
// LDS total 40KB -> 4 blocks/CU (4 independent barrier groups per CU).
// Counted vmcnt keeps next-step loads in flight across barriers.
// Epilogue: h [64][256] -> LDS (mix-swizzled, conflict-free), GEMM2 B-frags
// read straight from global w2t (identical across waves -> L1 broadcast).
__global__ __launch_bounds__(256, 4) void fused_kernel(
    const float* __restrict__ x, const unsigned short* __restrict__ w1t,
    const unsigned short* __restrict__ w2t, const float* __restrict__ b1,
    const float* __restrict__ b2, float* __restrict__ out) {
  __shared__ char smem[40960];
  unsigned short* const Abuf = (unsigned short*)smem;           // 2 x 4KB bf16
  unsigned short* const Bbuf = (unsigned short*)(smem + 8192);  // 2 x 16KB bf16

  const int t = threadIdx.x;
  const int lane = t & 63, wid = t >> 6;
  const int q = lane & 15, half = lane >> 4;
  const int bm = blockIdx.x;

  // ---- A staging: thread t owns chunk t (row t>>2, 8 k's at (t&3)*8) ----
  {
    int growA = bm * 64 + (t >> 2);
    if (growA > NROWS - 1) growA = NROWS - 1;
  }
  int growA = bm * 64 + (t >> 2);
  if (growA > NROWS - 1) growA = NROWS - 1;
  const float* const asrc = x + (size_t)growA * FIN + (t & 3) * 8;
  unsigned short* const adst = Abuf + t * 8;  // linear chunk t (byte t*16)

  float4 rA[2][2];
  auto load_A = [&](int slot, int k0) {
    rA[slot][0] = *(const float4*)(asrc + k0);
    rA[slot][1] = *(const float4*)(asrc + k0 + 4);
  };
  auto write_A = [&](int slot, int buf) {
    const float4 a0 = rA[slot][0], a1 = rA[slot][1];
    uint4 u;
    u.x = cvt_pk_bf16(a0.x, a0.y);
    u.y = cvt_pk_bf16(a0.z, a0.w);
    u.z = cvt_pk_bf16(a1.x, a1.y);
    u.w = cvt_pk_bf16(a1.z, a1.w);
    *(uint4*)(adst + buf * 2048) = u;
  };

  // ---- B staging: 1024 chunks of 16B, 4/thread; lds chunk (col,s) holds
  //      global chunk s ^ ((col>>2)&3) ----
  const unsigned short* bsrc[4];
  int bdst[4];
#pragma unroll
  for (int i = 0; i < 4; ++i) {
    const int c = t + i * 256;
    const int col = c >> 2, s = c & 3;
    bsrc[i] = w1t + (size_t)col * FIN + ((s ^ ((col >> 2) & 3)) << 3);
    bdst[i] = c * 8;
  }
  auto stage_B = [&](int buf, int k0) {
#pragma unroll
    for (int i = 0; i < 4; ++i)
      gload_lds16(bsrc[i] + k0, Bbuf + buf * 8192 + bdst[i]);
  };

  f32x4 acc[4][4];
  const f32x4 z4 = {0.f, 0.f, 0.f, 0.f};
#pragma unroll
  for (int m = 0; m < 4; ++m)
#pragma unroll
    for (int n = 0; n < 4; ++n) acc[m][n] = z4;

  auto compute = [&](int cur) {
    const unsigned short* Ac = Abuf + cur * 2048;
    const unsigned short* Bc = Bbuf + cur * 8192;
    s16x8 af[4];
#pragma unroll
    for (int m = 0; m < 4; ++m)
      af[m] = *(const s16x8*)(Ac + (m * 16 + q) * 32 + half * 8);
#pragma unroll
    for (int n = 0; n < 4; ++n) {
      const int col = wid * 64 + n * 16 + q;
      s16x8 bf = *(const s16x8*)(Bc + col * 32 + ((half ^ ((q >> 2) & 3)) << 3));
#pragma unroll
      for (int m = 0; m < 4; ++m) acc[m][n] = mfma_bf16(af[m], bf, acc[m][n]);
    }
  };

  // ---- prologue: B(0) DMA, A(0)/A(1) regs; drain B(0)+A(0); write A(0) ----
  stage_B(0, 0);
  load_A(0, 0);
  load_A(1, 32);
  asm volatile("s_waitcnt vmcnt(2)" ::: "memory");  // B(0), A(0) done; A(1) flies
  write_A(0, 0);

  for (int ks = 0; ks < 15; ++ks) {
    const int cur = ks & 1;
    if (ks < 14) {
      load_A(cur, (ks + 2) * 32);          // A(ks+2) -> regs (2 steps ahead)
      stage_B(cur ^ 1, (ks + 1) * 32);     // B(ks+1) DMA
      asm volatile("s_waitcnt vmcnt(6)" ::: "memory");  // A(ks+1) regs + B(ks) in
    } else {
      stage_B(cur ^ 1, (ks + 1) * 32);
      asm volatile("s_waitcnt vmcnt(4)" ::: "memory");
    }
    write_A(cur ^ 1, cur ^ 1);             // A(ks+1) -> LDS buf^1
    asm volatile("s_waitcnt lgkmcnt(0)" ::: "memory");
    __builtin_amdgcn_s_barrier();          // step-ks data ready everywhere
    __builtin_amdgcn_sched_barrier(0);
    compute(cur);
    __builtin_amdgcn_s_barrier();          // reads of buf cur done
    __builtin_amdgcn_sched_barrier(0);
  }
  // ks = 15
  asm volatile("s_waitcnt vmcnt(0)" ::: "memory");
  __builtin_amdgcn_s_barrier();
  __builtin_amdgcn_sched_barrier(0);
  compute(1);
  __syncthreads();

  // ================= epilogue =================
  unsigned short* const hls = (unsigned short*)(smem + 8192);  // [64][256] 32KB

  // h-write: element (rl,col) at rl*256 + ch*8 + (col&7), ch = (col>>3)^mix(rl)
  // mix(rl) = (rl&7) ^ (((rl>>3)&1)<<1): full 8-bank-group spread per instr.
#pragma unroll
  for (int n = 0; n < 4; ++n) {
    const int col = wid * 64 + n * 16 + q;
    const float bias = b1[col];
    const int c3 = col >> 3, c7 = col & 7;
#pragma unroll
    for (int m = 0; m < 4; ++m) {
#pragma unroll
      for (int r = 0; r < 4; ++r) {
        const int rl = m * 16 + half * 4 + r;
        const int mix = (rl & 7) ^ (((rl >> 3) & 1) << 1);
        float v = fmaxf(acc[m][n][r] + bias, 0.0f);
        hls[rl * 256 + ((c3 ^ mix) << 3) + c7] = f2bf(v);
      }
    }
  }
  __syncthreads();

  // GEMM2: out[64][64] ; wave owns rows wid*16..+15. B-frags from global w2t.
  f32x4 acc2[4];
#pragma unroll
  for (int n = 0; n < 4; ++n) acc2[n] = z4;
  const int arl = wid * 16 + q;
  const int mixa = (q & 7) ^ ((q >> 3) << 1);
#pragma unroll
  for (int j = 0; j < 8; ++j) {
    const int kc = j * 4 + half;
    s16x8 a2 = *(const s16x8*)(hls + arl * 256 + ((kc ^ mixa) << 3));
#pragma unroll
    for (int n = 0; n < 4; ++n) {
      const int c = n * 16 + q;
      s16x8 bfp = *(const s16x8*)(w2t + (size_t)c * HIDDEN + j * 32 + half * 8);
      acc2[n] = mfma_bf16(a2, bfp, acc2[n]);
    }
  }

  float bias2[4];
#pragma unroll
  for (int n = 0; n < 4; ++n) {
    const int c = n * 16 + q;
    bias2[n] = (c < NCLS) ? b2[c] : 0.0f;
  }
#pragma unroll
  for (int r = 0; r < 4; ++r) {
    float vals[4];
    float mx = -1e30f;
#pragma unroll
    for (int n = 0; n < 4; ++n) {
      const int c = n * 16 + q;
      float v = acc2[n][r] + bias2[n];
      vals[n] = v;
      if (c < NCLS) mx = fmaxf(mx, v);
    }
    for (int off = 8; off >= 1; off >>= 1)
      mx = fmaxf(mx, __shfl_xor(mx, off, 64));
    float s = 0.f;
#pragma unroll
    for (int n = 0; n < 4; ++n) {
      const int c = n * 16 + q;
      if (c < NCLS) s += __expf(vals[n] - mx);
    }
    for (int off = 8; off >= 1; off >>= 1) s += __shfl_xor(s, off, 64);
    const float lz = __logf(s);
    const int rowg = bm * 64 + wid * 16 + half * 4 + r;
    if (rowg < NROWS) {
#pragma unroll
      for (int n = 0; n < 4; ++n) {
        const int c = n * 16 + q;
        if (c < NCLS) out[(size_t)rowg * NCLS + c] = vals[n] - mx - lz;
      }
    }
  }
}

extern "C" void kernel_launch(void* const* d_in, const int* in_sizes, int n_in,
                              void* d_out, int out_size, void* d_ws, size_t ws_size,
                              hipStream_t stream) {
  const float* x  = (const float*)d_in[0];
  // d_in[1] = edge_index: dead (ALPHA==1.0 makes APPNP the identity)
  const float* W1 = (const float*)d_in[2];
  const float* b1 = (const float*)d_in[3];
  const float* W2 = (const float*)d_in[4];
  const float* b2 = (const float*)d_in[5];
  float* out = (float*)d_out;

  char* ws = (char*)d_ws;
  unsigned short* w1t = (unsigned short*)(ws);           // 256 KB
  unsigned short* w2t = (unsigned short*)(ws + 262144);  // 32 KB

  prep_kernel<<<36, 256, 0, stream>>>(W1, W2, w1t, w2t);
  fused_kernel<<<(NROWS + 63) / 64, 256, 0, stream>>>(x, w1t, w2t, b1, b2, out);
}